// Round 1
// baseline (310.147 us; speedup 1.0000x reference)
//
#include <hip/hip_runtime.h>

// PatternAwareLoss: BCE-with-logits + neighbor pattern boost + masked mean.
// Shapes fixed by setup_inputs(): B=64, S=8192, L=24.
constexpr int B = 64;
constexpr int S = 8192;
constexpr int L = 24;          // 24 = 6 * int4/float4
constexpr int NPOS = B * S;    // 524288 positions
constexpr float BOOST = 1.2f;

__device__ __forceinline__ float bce(float x, float y) {
    // max(x,0) - x*y + log1p(exp(-|x|))
    return fmaxf(x, 0.0f) - x * y + log1pf(expf(-fabsf(x)));
}

__global__ __launch_bounds__(256) void pal_kernel(
    const float* __restrict__ logits,
    const int*   __restrict__ labels,
    const float* __restrict__ mask,
    double*      __restrict__ acc)   // acc[0] = sum(loss*boost*mask), acc[1] = sum(mask)
{
    __shared__ unsigned char hp_sh[257];

    const int t = threadIdx.x;
    const int p = blockIdx.x * blockDim.x + t;   // position index; grid covers NPOS exactly
    const int s = p & (S - 1);                   // S is pow2

    // ---- load this position's 24 labels once (registers), compute has_punct ----
    const int4* lab4 = (const int4*)(labels + (size_t)p * L);
    int4 lab[6];
    int lsum = 0;
#pragma unroll
    for (int j = 0; j < 6; ++j) {
        lab[j] = lab4[j];
        lsum += lab[j].x + lab[j].y + lab[j].z + lab[j].w;
    }
    const int hp = (lsum > 0) ? 1 : 0;
    hp_sh[t] = (unsigned char)hp;

    // boundary thread also computes has_punct for position p+1 (next block's first pos)
    if (t == blockDim.x - 1) {
        int hpn = 0;
        if (s < S - 1) {   // s == S-1 never boosts, skip
            const int4* labn = (const int4*)(labels + (size_t)(p + 1) * L);
            int sn = 0;
#pragma unroll
            for (int j = 0; j < 6; ++j) {
                int4 v = labn[j];
                sn += v.x + v.y + v.z + v.w;
            }
            hpn = (sn > 0) ? 1 : 0;
        }
        hp_sh[blockDim.x] = (unsigned char)hpn;
    }
    __syncthreads();

    // ---- BCE loss sum over the 24 logits of this position ----
    const float4* lg4 = (const float4*)(logits + (size_t)p * L);
    float ls = 0.0f;
#pragma unroll
    for (int j = 0; j < 6; ++j) {
        float4 v = lg4[j];
        ls += bce(v.x, (float)lab[j].x);
        ls += bce(v.y, (float)lab[j].y);
        ls += bce(v.z, (float)lab[j].z);
        ls += bce(v.w, (float)lab[j].w);
    }

    // ---- boost + mask ----
    float boost = 1.0f;
    if (s < S - 1 && hp && hp_sh[t + 1]) boost = BOOST;
    float m = mask[p];
    float contrib = ls * boost * m;

    // ---- wave-64 reduction, then one double atomic per wave ----
#pragma unroll
    for (int off = 32; off > 0; off >>= 1) {
        contrib += __shfl_down(contrib, off, 64);
        m       += __shfl_down(m, off, 64);
    }
    if ((t & 63) == 0) {
        atomicAdd(&acc[0], (double)contrib);
        atomicAdd(&acc[1], (double)m);
    }
}

__global__ void pal_finalize(const double* __restrict__ acc, float* __restrict__ out) {
    out[0] = (float)(acc[0] / acc[1]);   // denominator = sum(attention_mask), NOT *L
}

extern "C" void kernel_launch(void* const* d_in, const int* in_sizes, int n_in,
                              void* d_out, int out_size, void* d_ws, size_t ws_size,
                              hipStream_t stream) {
    const float* logits = (const float*)d_in[0];
    const int*   labels = (const int*)d_in[1];
    const float* mask   = (const float*)d_in[2];
    float*  out = (float*)d_out;
    double* acc = (double*)d_ws;

    // d_ws is re-poisoned to 0xAA before every launch — zero the accumulators.
    hipMemsetAsync(d_ws, 0, 2 * sizeof(double), stream);

    pal_kernel<<<NPOS / 256, 256, 0, stream>>>(logits, labels, mask, acc);
    pal_finalize<<<1, 1, 0, stream>>>(acc, out);
}

// Round 2
// 139.113 us; speedup vs baseline: 2.2295x; 2.2295x over previous
//
#include <hip/hip_runtime.h>

// PatternAwareLoss, coalesced restructure.
// B=64, S=8192, L=24. L%4==0 -> every 16B chunk lies within one position.
constexpr int Bdim = 64;
constexpr int S = 8192;
constexpr int L = 24;
constexpr int NPOS = Bdim * S;         // 524288 positions
constexpr int NCHUNK = NPOS * (L / 4); // 3,145,728 float4/int4 chunks
constexpr float BOOST = 1.2f;
constexpr int NBLK_B = 256;            // kernel B grid

__device__ __forceinline__ float bce(float x, float yi) {
    return fmaxf(x, 0.0f) - x * yi + log1pf(expf(-fabsf(x)));
}

// ---- Kernel A: coalesced BCE + per-position loss / has_punct ----
// Block of 256 threads handles 128 positions = 768 chunks.
// Global loads: lane i reads chunk base+i -> contiguous 16B/lane, perfect.
__global__ __launch_bounds__(256) void pal_bce(
    const float* __restrict__ logits,
    const int*   __restrict__ labels,
    float*         __restrict__ loss_ws,  // [NPOS]
    unsigned char* __restrict__ hp_ws)    // [NPOS]
{
    __shared__ float psum[768];
    __shared__ float plab[768];
    const int t = threadIdx.x;
    const size_t base = (size_t)blockIdx.x * 768;

#pragma unroll
    for (int k = 0; k < 3; ++k) {
        const size_t c = base + (size_t)t + 256 * k;
        float4 lg = ((const float4*)logits)[c];
        int4   lb = ((const int4*)labels)[c];
        float s = 0.0f;
        s += bce(lg.x, (float)lb.x);
        s += bce(lg.y, (float)lb.y);
        s += bce(lg.z, (float)lb.z);
        s += bce(lg.w, (float)lb.w);
        psum[t + 256 * k] = s;
        plab[t + 256 * k] = (float)(lb.x + lb.y + lb.z + lb.w);
    }
    __syncthreads();

    if (t < 128) {
        float ls = 0.0f, lab = 0.0f;
#pragma unroll
        for (int j = 0; j < 6; ++j) {
            ls  += psum[6 * t + j];
            lab += plab[6 * t + j];
        }
        const size_t p = (size_t)blockIdx.x * 128 + t;
        loss_ws[p] = ls;
        hp_ws[p]   = (lab > 0.0f) ? 1 : 0;   // exact: sums of small ints
    }
}

// ---- Kernel B: boost + mask + deterministic block partials (no atomics) ----
__global__ __launch_bounds__(256) void pal_boost(
    const float*         __restrict__ loss_ws,
    const unsigned char* __restrict__ hp_ws,
    const float*         __restrict__ mask,
    double*              __restrict__ partials)   // [2 * NBLK_B]
{
    double lsum = 0.0, msum = 0.0;
    const int stride = gridDim.x * blockDim.x;
    for (int p = blockIdx.x * blockDim.x + threadIdx.x; p < NPOS; p += stride) {
        const int s = p & (S - 1);
        float ls = loss_ws[p];
        float m  = mask[p];
        float boost = (s < S - 1 && hp_ws[p] && hp_ws[p + 1]) ? BOOST : 1.0f;
        lsum += (double)(ls * boost * m);
        msum += (double)m;
    }
    __shared__ double sl[256], sm[256];
    sl[threadIdx.x] = lsum;
    sm[threadIdx.x] = msum;
    __syncthreads();
    for (int off = 128; off > 0; off >>= 1) {
        if (threadIdx.x < off) {
            sl[threadIdx.x] += sl[threadIdx.x + off];
            sm[threadIdx.x] += sm[threadIdx.x + off];
        }
        __syncthreads();
    }
    if (threadIdx.x == 0) {
        partials[2 * blockIdx.x]     = sl[0];
        partials[2 * blockIdx.x + 1] = sm[0];
    }
}

// ---- Kernel C: final reduce (256 partial pairs) + divide ----
__global__ __launch_bounds__(256) void pal_final(
    const double* __restrict__ partials,
    float*        __restrict__ out)
{
    const int t = threadIdx.x;
    double l = partials[2 * t];
    double m = partials[2 * t + 1];
    __shared__ double sl[256], sm[256];
    sl[t] = l; sm[t] = m;
    __syncthreads();
    for (int off = 128; off > 0; off >>= 1) {
        if (t < off) { sl[t] += sl[t + off]; sm[t] += sm[t + off]; }
        __syncthreads();
    }
    if (t == 0) out[0] = (float)(sl[0] / sm[0]);
}

extern "C" void kernel_launch(void* const* d_in, const int* in_sizes, int n_in,
                              void* d_out, int out_size, void* d_ws, size_t ws_size,
                              hipStream_t stream) {
    const float* logits = (const float*)d_in[0];
    const int*   labels = (const int*)d_in[1];
    const float* mask   = (const float*)d_in[2];
    float* out = (float*)d_out;

    // ws layout: loss (NPOS f32 = 2 MB) | hp (NPOS u8 = 512 KB) | partials (2*NBLK_B f64)
    char* ws = (char*)d_ws;
    float*         loss_ws  = (float*)ws;
    unsigned char* hp_ws    = (unsigned char*)(ws + (size_t)NPOS * sizeof(float));
    double*        partials = (double*)(ws + (size_t)NPOS * sizeof(float) + NPOS);

    pal_bce  <<<NPOS / 128, 256, 0, stream>>>(logits, labels, loss_ws, hp_ws);
    pal_boost<<<NBLK_B,     256, 0, stream>>>(loss_ws, hp_ws, mask, partials);
    pal_final<<<1,          256, 0, stream>>>(partials, out);
}

// Round 3
// 122.445 us; speedup vs baseline: 2.5329x; 1.1361x over previous
//
#include <hip/hip_runtime.h>

// PatternAwareLoss, fused single-pass + tiny finalize.
// B=64, S=8192, L=24. Blocks of 256 threads handle 128 consecutive positions
// (768 float4/int4 chunks, perfectly coalesced). 8192/128 = 64 blocks per row,
// so row boundaries align with block boundaries.
constexpr int Bdim = 64;
constexpr int S = 8192;
constexpr int L = 24;
constexpr int NPOS = Bdim * S;          // 524288
constexpr int POS_PER_BLK = 128;
constexpr int NBLK = NPOS / POS_PER_BLK; // 4096
constexpr int BLK_PER_ROW = S / POS_PER_BLK; // 64
constexpr float BOOST = 1.2f;

__device__ __forceinline__ float bce(float x, float y) {
    // max(x,0) - x*y + log1p(exp(-|x|)), with HW transcendentals.
    // exp(-|x|) in (0,1] -> log(1+e), e+1 in (1,2]: __logf precision ample here
    // (tolerance on final scalar is 0.465; this contributes ~1e-6).
    float e = __expf(-fabsf(x));
    float l = __logf(1.0f + e);
    return fmaxf(x, 0.0f) - x * y + l;
}

__global__ __launch_bounds__(256) void pal_main(
    const float* __restrict__ logits,
    const int*   __restrict__ labels,
    const float* __restrict__ mask,
    double*      __restrict__ partials)   // [2 * NBLK]
{
    __shared__ float psum[768];
    __shared__ float plab[768];
    __shared__ unsigned char hp_next_sh;   // has_punct of position base+128
    __shared__ float wl[4], wm[4];

    const int t = threadIdx.x;
    const size_t cbase = (size_t)blockIdx.x * 768;   // chunk base

    // t==0 peeks next block's first position labels (96 B) for the boundary
    // boost; zero if this is the last block of a row (s==S-1 never boosts).
    if (t == 0) {
        int hn = 0;
        if ((blockIdx.x & (BLK_PER_ROW - 1)) != BLK_PER_ROW - 1) {
            const int4* nb = (const int4*)labels + cbase + 768;
            int sn = 0;
#pragma unroll
            for (int j = 0; j < 6; ++j) { int4 v = nb[j]; sn += v.x + v.y + v.z + v.w; }
            hn = (sn > 0) ? 1 : 0;
        }
        hp_next_sh = (unsigned char)hn;
    }

#pragma unroll
    for (int k = 0; k < 3; ++k) {
        const size_t c = cbase + (size_t)t + 256 * k;
        float4 lg = ((const float4*)logits)[c];
        int4   lb = ((const int4*)labels)[c];
        float s = 0.0f;
        s += bce(lg.x, (float)lb.x);
        s += bce(lg.y, (float)lb.y);
        s += bce(lg.z, (float)lb.z);
        s += bce(lg.w, (float)lb.w);
        psum[t + 256 * k] = s;
        plab[t + 256 * k] = (float)(lb.x + lb.y + lb.z + lb.w);
    }
    __syncthreads();

    float contrib = 0.0f, m = 0.0f;
    if (t < POS_PER_BLK) {
        float ls = 0.0f, lab = 0.0f;
#pragma unroll
        for (int j = 0; j < 6; ++j) { ls += psum[6 * t + j]; lab += plab[6 * t + j]; }
        int hp = (lab > 0.0f);
        int hpn;
        if (t < POS_PER_BLK - 1) {
            float ln = 0.0f;
#pragma unroll
            for (int j = 0; j < 6; ++j) ln += plab[6 * t + 6 + j];
            hpn = (ln > 0.0f);
        } else {
            hpn = hp_next_sh;
        }
        // Within a block, s = s0 + t with s0 ≡ 0 (mod 128); t<127 -> s < S-1
        // always; t==127 last-block-in-row case handled via hp_next_sh = 0.
        float boost = (hp && hpn) ? BOOST : 1.0f;
        m = mask[(size_t)blockIdx.x * POS_PER_BLK + t];
        contrib = ls * boost * m;
    }

    // deterministic reduce: wave shuffles, then thread 0 folds 4 wave sums
#pragma unroll
    for (int off = 32; off > 0; off >>= 1) {
        contrib += __shfl_down(contrib, off, 64);
        m       += __shfl_down(m, off, 64);
    }
    if ((t & 63) == 0) { wl[t >> 6] = contrib; wm[t >> 6] = m; }
    __syncthreads();
    if (t == 0) {
        double Ls = (double)wl[0] + (double)wl[1] + (double)wl[2] + (double)wl[3];
        double Ms = (double)wm[0] + (double)wm[1] + (double)wm[2] + (double)wm[3];
        partials[2 * blockIdx.x]     = Ls;
        partials[2 * blockIdx.x + 1] = Ms;
    }
}

__global__ __launch_bounds__(256) void pal_final(
    const double* __restrict__ partials,
    float*        __restrict__ out)
{
    const int t = threadIdx.x;
    double l = 0.0, m = 0.0;
    for (int i = t; i < NBLK; i += 256) {
        l += partials[2 * i];
        m += partials[2 * i + 1];
    }
    __shared__ double sl[256], sm[256];
    sl[t] = l; sm[t] = m;
    __syncthreads();
    for (int off = 128; off > 0; off >>= 1) {
        if (t < off) { sl[t] += sl[t + off]; sm[t] += sm[t + off]; }
        __syncthreads();
    }
    if (t == 0) out[0] = (float)(sl[0] / sm[0]);
}

extern "C" void kernel_launch(void* const* d_in, const int* in_sizes, int n_in,
                              void* d_out, int out_size, void* d_ws, size_t ws_size,
                              hipStream_t stream) {
    const float* logits = (const float*)d_in[0];
    const int*   labels = (const int*)d_in[1];
    const float* mask   = (const float*)d_in[2];
    float*  out = (float*)d_out;
    double* partials = (double*)d_ws;   // 2*NBLK doubles = 64 KB, written before read

    pal_main <<<NBLK, 256, 0, stream>>>(logits, labels, mask, partials);
    pal_final<<<1,    256, 0, stream>>>(partials, out);
}